// Round 12
// baseline (321.004 us; speedup 1.0000x reference)
//
#include <hip/hip_runtime.h>
#include <math.h>

#define N_NODES 100000
#define N_EDGES 1200000
#define N_GRAPHS 1000
#define HID 64
#define NBUCK 256
#define NPB   391            // ceil(100000/256)
#define EDGE_CHUNK 16384
#define S3_BLOCKS ((N_EDGES + EDGE_CHUNK - 1) / EDGE_CHUNK)   // 74
#define NODE_BLOCKS ((N_NODES + 255) / 256)                    // 391
#define DBINS 64
#define LOG2E 1.4426950408889634f

typedef _Float16 half_t;
typedef __attribute__((ext_vector_type(4))) _Float16 half4;

// ---------------- CSR build via 2-level bucket sort --------------------------
// staged entry: (local_dst << 17) | src   (src < 2^17, local_dst < 512)

__global__ void k_bhist(const int* __restrict__ ei, int* __restrict__ bucket_cnt) {
    __shared__ int hist[NBUCK];
    for (int t = threadIdx.x; t < NBUCK; t += blockDim.x) hist[t] = 0;
    __syncthreads();
    int e0 = blockIdx.x * EDGE_CHUNK;
    int e1 = min(e0 + EDGE_CHUNK, N_EDGES);
    for (int e = e0 + threadIdx.x; e < e1; e += blockDim.x)
        atomicAdd(&hist[ei[N_EDGES + e] / NPB], 1);
    __syncthreads();
    for (int t = threadIdx.x; t < NBUCK; t += blockDim.x)
        if (hist[t]) atomicAdd(&bucket_cnt[t], hist[t]);
}

__global__ void k_bscan(const int* __restrict__ bucket_cnt, int* __restrict__ bucket_base) {
    __shared__ int sh[NBUCK];
    int t = threadIdx.x;
    int v = bucket_cnt[t];
    sh[t] = v;
    __syncthreads();
    for (int off = 1; off < NBUCK; off <<= 1) {
        int u = (t >= off) ? sh[t - off] : 0;
        __syncthreads();
        sh[t] += u;
        __syncthreads();
    }
    bucket_base[t] = sh[t] - v;               // exclusive
    if (t == NBUCK - 1) bucket_base[NBUCK] = sh[t];
}

__global__ void k_bin(const int* __restrict__ ei, const int* __restrict__ bucket_base,
                      int* __restrict__ bucket_fill, int* __restrict__ staged) {
    __shared__ int hist[NBUCK];
    __shared__ int cursor[NBUCK];
    for (int t = threadIdx.x; t < NBUCK; t += blockDim.x) hist[t] = 0;
    __syncthreads();
    int e0 = blockIdx.x * EDGE_CHUNK;
    int e1 = min(e0 + EDGE_CHUNK, N_EDGES);
    for (int e = e0 + threadIdx.x; e < e1; e += blockDim.x)
        atomicAdd(&hist[ei[N_EDGES + e] / NPB], 1);
    __syncthreads();
    if (threadIdx.x < NBUCK) {
        int hv = hist[threadIdx.x];
        int start = bucket_base[threadIdx.x];
        if (hv) start += atomicAdd(&bucket_fill[threadIdx.x], hv);
        cursor[threadIdx.x] = start;
    }
    __syncthreads();
    for (int e = e0 + threadIdx.x; e < e1; e += blockDim.x) {
        int src = ei[e], dst = ei[N_EDGES + e];
        int b = dst / NPB;
        int ldst = dst - b * NPB;
        int pos = atomicAdd(&cursor[b], 1);
        staged[pos] = (ldst << 17) | src;
    }
}

__global__ void k_bcsr(const int* __restrict__ staged, const int* __restrict__ bucket_base,
                       int* __restrict__ rowptr, int* __restrict__ csr_src) {
    __shared__ int ldeg[NPB];
    __shared__ int sc[512];
    __shared__ int cursor[NPB];
    int b = blockIdx.x;
    int n0 = b * NPB;
    int n1 = min(n0 + NPB, N_NODES);
    int nn = n1 - n0;
    int bbase = bucket_base[b];
    int bcnt  = bucket_base[b+1] - bbase;
    for (int t = threadIdx.x; t < NPB; t += blockDim.x) ldeg[t] = 0;
    __syncthreads();
    for (int k = threadIdx.x; k < bcnt; k += blockDim.x)
        atomicAdd(&ldeg[staged[bbase + k] >> 17], 1);
    __syncthreads();
    if (threadIdx.x < 512) sc[threadIdx.x] = (threadIdx.x < nn) ? ldeg[threadIdx.x] : 0;
    __syncthreads();
    for (int off = 1; off < 512; off <<= 1) {
        int u = 0;
        if (threadIdx.x < 512 && threadIdx.x >= off) u = sc[threadIdx.x - off];
        __syncthreads();
        if (threadIdx.x < 512) sc[threadIdx.x] += u;
        __syncthreads();
    }
    if (threadIdx.x < nn) {
        int pre = sc[threadIdx.x] - ldeg[threadIdx.x];     // exclusive
        rowptr[n0 + threadIdx.x] = bbase + pre;
        cursor[threadIdx.x] = bbase + pre;
    }
    if (b == 0 && threadIdx.x == 0) rowptr[N_NODES] = bucket_base[NBUCK];
    __syncthreads();
    for (int k = threadIdx.x; k < bcnt; k += blockDim.x) {
        int v = staged[bbase + k];
        int pos = atomicAdd(&cursor[v >> 17], 1);
        csr_src[pos] = v & 0x1FFFF;
    }
}

// ---------------- degree-sorted node order (anti-divergence) -----------------

__global__ void k_dhist(const int* __restrict__ rowptr, int* __restrict__ dbin) {
    __shared__ int h[DBINS];
    if (threadIdx.x < DBINS) h[threadIdx.x] = 0;
    __syncthreads();
    int i = blockIdx.x * 256 + threadIdx.x;
    if (i < N_NODES) {
        int d = min(rowptr[i+1] - rowptr[i], DBINS - 1);
        atomicAdd(&h[d], 1);
    }
    __syncthreads();
    if (threadIdx.x < DBINS && h[threadIdx.x])
        atomicAdd(&dbin[threadIdx.x], h[threadIdx.x]);
}

__global__ void k_dscan(const int* __restrict__ dbin, int* __restrict__ dfill) {
    __shared__ int sh[DBINS];
    int t = threadIdx.x;
    int v = dbin[t];
    sh[t] = v;
    __syncthreads();
    for (int off = 1; off < DBINS; off <<= 1) {
        int u = (t >= off) ? sh[t - off] : 0;
        __syncthreads();
        sh[t] += u;
        __syncthreads();
    }
    dfill[t] = sh[t] - v;                     // exclusive prefix
}

__global__ void k_dscatter(const int* __restrict__ rowptr, int* __restrict__ dfill,
                           int* __restrict__ nodeorder) {
    __shared__ int h[DBINS];
    __shared__ int cur[DBINS];
    if (threadIdx.x < DBINS) h[threadIdx.x] = 0;
    __syncthreads();
    int i = blockIdx.x * 256 + threadIdx.x;
    int d = -1;
    if (i < N_NODES) {
        d = min(rowptr[i+1] - rowptr[i], DBINS - 1);
        atomicAdd(&h[d], 1);
    }
    __syncthreads();
    if (threadIdx.x < DBINS) {
        int hv = h[threadIdx.x];
        cur[threadIdx.x] = hv ? atomicAdd(&dfill[threadIdx.x], hv) : 0;
    }
    __syncthreads();
    if (i < N_NODES) {
        int pos = atomicAdd(&cur[d], 1);
        nodeorder[pos] = i;
    }
}

// ---------------- fused climber LN + FiLM coefficient kernel -----------------
__global__ void k_climber_film(const float* __restrict__ climber,
                               const float* __restrict__ ln_g, const float* __restrict__ ln_b,
                               const float* __restrict__ W_c, const float* __restrict__ b_c,
                               const float* __restrict__ Wf1, const float* __restrict__ bf1,
                               const float* __restrict__ Wf2, const float* __restrict__ bf2,
                               float* __restrict__ gb1, float* __restrict__ gb2) {
    __shared__ float cl[64];
    int g = blockIdx.x;
    int j = threadIdx.x;
    if (j < 64) {
        float v[6];
        float mu = 0.f;
        #pragma unroll
        for (int k = 0; k < 6; k++) { v[k] = climber[g*6+k]; mu += v[k]; }
        mu *= (1.f/6.f);
        float var = 0.f;
        #pragma unroll
        for (int k = 0; k < 6; k++) { float d = v[k]-mu; var += d*d; }
        var *= (1.f/6.f);
        float rs = rsqrtf(var + 1e-5f);
        float acc = b_c[j];
        #pragma unroll
        for (int k = 0; k < 6; k++) {
            float cn = (v[k]-mu)*rs*ln_g[k] + ln_b[k];
            acc += cn * W_c[k*64+j];
        }
        cl[j] = fmaxf(acc, 0.f);
    }
    __syncthreads();
    float a1 = bf1[j], a2 = bf2[j];
    #pragma unroll 8
    for (int k = 0; k < 64; k++) {
        float ck = cl[k];
        a1 += ck * Wf1[k*128+j];
        a2 += ck * Wf2[k*128+j];
    }
    gb1[g*128+j] = a1;
    gb2[g*128+j] = a2;
}

// ---------------- fused node kernels ----------------------------------------
// Layout: 4 nodes per wave, 16 lanes/node, lane sl holds features 4sl..4sl+3.
// z fp16; es/ed pre-scaled by log2(e) so per-edge exp is a bare v_exp_f32.

__device__ __forceinline__ float4 h4_to_f4(half4 h) {
    float4 f;
    f.x = (float)h.x; f.y = (float)h.y; f.z = (float)h.z; f.w = (float)h.w;
    return f;
}

__device__ __forceinline__ float4 gat_core(int i, int sl,
    const int* __restrict__ rowptr, const int* __restrict__ csr_src,
    const float* __restrict__ es, const float* __restrict__ ed,
    const half_t* __restrict__ z, const float* __restrict__ bg) {
    int beg = rowptr[i], end = rowptr[i+1];
    int deg = end - beg;
    float edi = ed[i];

    float e_self = es[i] + edi;
    e_self = fmaxf(e_self, 0.2f * e_self);

    // cache up to 32 edges: bank A = edges [0,16), bank B = [16,32)
    int svA = 0, svB = 0;
    float scA = -1e30f, scB = -1e30f;
    if (sl < deg) {
        svA = csr_src[beg + sl];
        float v = es[svA] + edi;
        scA = fmaxf(v, 0.2f * v);
    }
    if (16 + sl < deg) {
        svB = csr_src[beg + 16 + sl];
        float v = es[svB] + edi;
        scB = fmaxf(v, 0.2f * v);
    }
    float t = fmaxf(scA, scB);
    for (int k = beg + 32 + sl; k < end; k += 16) {   // rare: deg > 32
        int s2 = csr_src[k];
        float v = es[s2] + edi;
        t = fmaxf(t, fmaxf(v, 0.2f * v));
    }
    #pragma unroll
    for (int off = 1; off < 16; off <<= 1)
        t = fmaxf(t, __shfl_xor(t, off, 16));
    float m = fmaxf(e_self, t);

    const half4* z4 = (const half4*)z;
    float ex = exp2f(e_self - m);
    float s = ex;
    float4 zi = h4_to_f4(z4[i*16 + sl]);
    float4 acc = {ex*zi.x, ex*zi.y, ex*zi.z, ex*zi.w};

    int lim = (deg < 32) ? deg : 32;
    int k = 0;
    for (; k + 8 <= lim; k += 8) {
        int a[8]; float c[8];
        if (k < 16) {
            #pragma unroll
            for (int j = 0; j < 8; j++) {
                a[j] = __shfl(svA, k+j, 16);
                c[j] = __shfl(scA, k+j, 16);
            }
        } else {
            #pragma unroll
            for (int j = 0; j < 8; j++) {
                a[j] = __shfl(svB, k-16+j, 16);
                c[j] = __shfl(scB, k-16+j, 16);
            }
        }
        half4 q[8];
        #pragma unroll
        for (int j = 0; j < 8; j++) q[j] = z4[a[j]*16 + sl];
        float e[8];
        #pragma unroll
        for (int j = 0; j < 8; j++) e[j] = exp2f(c[j] - m);
        #pragma unroll
        for (int j = 0; j < 8; j++) {
            float4 r = h4_to_f4(q[j]);
            s += e[j];
            acc.x += e[j]*r.x; acc.y += e[j]*r.y;
            acc.z += e[j]*r.z; acc.w += e[j]*r.w;
        }
    }
    for (; k + 4 <= lim; k += 4) {
        int a[4]; float c[4];
        if (k < 16) {
            #pragma unroll
            for (int j = 0; j < 4; j++) {
                a[j] = __shfl(svA, k+j, 16);
                c[j] = __shfl(scA, k+j, 16);
            }
        } else {
            #pragma unroll
            for (int j = 0; j < 4; j++) {
                a[j] = __shfl(svB, k-16+j, 16);
                c[j] = __shfl(scB, k-16+j, 16);
            }
        }
        half4 q[4];
        #pragma unroll
        for (int j = 0; j < 4; j++) q[j] = z4[a[j]*16 + sl];
        #pragma unroll
        for (int j = 0; j < 4; j++) {
            float e2 = exp2f(c[j] - m);
            float4 r = h4_to_f4(q[j]);
            s += e2;
            acc.x += e2*r.x; acc.y += e2*r.y; acc.z += e2*r.z; acc.w += e2*r.w;
        }
    }
    for (; k < lim; k++) {
        int a; float cv;
        if (k < 16) { a = __shfl(svA, k, 16);    cv = __shfl(scA, k, 16); }
        else        { a = __shfl(svB, k-16, 16); cv = __shfl(scB, k-16, 16); }
        float e2 = exp2f(cv - m);
        s += e2;
        float4 zr = h4_to_f4(z4[a*16 + sl]);
        acc.x += e2*zr.x; acc.y += e2*zr.y; acc.z += e2*zr.z; acc.w += e2*zr.w;
    }
    for (int kk = beg + 32; kk < end; kk++) {   // rare fallback
        int sv = csr_src[kk];
        float v = es[sv] + edi;
        v = fmaxf(v, 0.2f * v);
        float e2 = exp2f(v - m);
        s += e2;
        float4 zr = h4_to_f4(z4[sv*16 + sl]);
        acc.x += e2*zr.x; acc.y += e2*zr.y; acc.z += e2*zr.z; acc.w += e2*zr.w;
    }
    float inv = 1.f / (s + 1e-16f);
    float4 bg4 = ((const float4*)bg)[sl];
    float4 o;
    o.x = fmaxf(acc.x*inv + bg4.x, 0.f);
    o.y = fmaxf(acc.y*inv + bg4.y, 0.f);
    o.z = fmaxf(acc.z*inv + bg4.z, 0.f);
    o.w = fmaxf(acc.w*inv + bg4.w, 0.f);
    return o;
}

__device__ __forceinline__ float4 rowmat16(float4 hr, int sl, const float4* Wl) {
    float hv[4] = {hr.x, hr.y, hr.z, hr.w};
    float4 acc = {0.f, 0.f, 0.f, 0.f};
    #pragma unroll
    for (int k = 0; k < 64; k++) {
        float hk = __shfl(hv[k & 3], k >> 2, 16);
        float4 w = Wl[k*16 + sl];
        acc.x += hk*w.x; acc.y += hk*w.y; acc.z += hk*w.z; acc.w += hk*w.w;
    }
    return acc;
}

// stores es/ed PRE-SCALED by log2(e)
__device__ __forceinline__ void attn_proj(float4 zc, int sl,
    const float* __restrict__ a_src, const float* __restrict__ a_dst,
    int i, float* __restrict__ es, float* __restrict__ ed) {
    float4 as4 = ((const float4*)a_src)[sl];
    float4 ad4 = ((const float4*)a_dst)[sl];
    float ps = zc.x*as4.x + zc.y*as4.y + zc.z*as4.z + zc.w*as4.w;
    float pd = zc.x*ad4.x + zc.y*ad4.y + zc.z*ad4.z + zc.w*ad4.w;
    #pragma unroll
    for (int off = 1; off < 16; off <<= 1) {
        ps += __shfl_xor(ps, off, 16);
        pd += __shfl_xor(pd, off, 16);
    }
    if (sl == 0) { es[i] = ps * LOG2E; ed[i] = pd * LOG2E; }
}

__device__ __forceinline__ void store_z_h4(half_t* z, int i, int sl, float4 zc) {
    half4 h;
    h.x = (half_t)zc.x; h.y = (half_t)zc.y; h.z = (half_t)zc.z; h.w = (half_t)zc.w;
    ((half4*)z)[i*16 + sl] = h;
}

__global__ void k_layer1(const float* __restrict__ x, const int* __restrict__ batch,
                         const float* __restrict__ W_in, const float* __restrict__ b_in,
                         const float* __restrict__ gb1, const float* __restrict__ Wg1,
                         const float* __restrict__ as1, const float* __restrict__ ad1,
                         half_t* __restrict__ z1, float* __restrict__ es1,
                         float* __restrict__ ed1) {
    __shared__ float4 Wl[1024];
    const float4* Wg4 = (const float4*)Wg1;
    for (int t = threadIdx.x; t < 1024; t += blockDim.x) Wl[t] = Wg4[t];
    int tid = blockIdx.x * blockDim.x + threadIdx.x;
    int i  = tid >> 4;
    int sl = threadIdx.x & 15;
    __syncthreads();
    if (i >= N_NODES) return;
    float4 acc = ((const float4*)b_in)[sl];
    #pragma unroll
    for (int k = 0; k < 6; k++) {
        float xk = x[i*8+k];
        float4 w = ((const float4*)W_in)[k*16 + sl];
        acc.x += xk*w.x; acc.y += xk*w.y; acc.z += xk*w.z; acc.w += xk*w.w;
    }
    int g = batch[i];
    const float4* gb4 = (const float4*)gb1;
    float4 ga = gb4[g*32 + sl];
    float4 be = gb4[g*32 + 16 + sl];
    acc.x = acc.x*(1.f+ga.x) + be.x;
    acc.y = acc.y*(1.f+ga.y) + be.y;
    acc.z = acc.z*(1.f+ga.z) + be.z;
    acc.w = acc.w*(1.f+ga.w) + be.w;
    float4 zc = rowmat16(acc, sl, Wl);
    store_z_h4(z1, i, sl, zc);
    attn_proj(zc, sl, as1, ad1, i, es1, ed1);
}

__global__ void k_layer2(const int* __restrict__ nodeorder,
                         const int* __restrict__ rowptr, const int* __restrict__ csr_src,
                         const float* __restrict__ es1, const float* __restrict__ ed1,
                         const half_t* __restrict__ z1, const float* __restrict__ bg1,
                         const int* __restrict__ batch, const float* __restrict__ gb2,
                         const float* __restrict__ Wg2, const float* __restrict__ as2,
                         const float* __restrict__ ad2,
                         half_t* __restrict__ z2, float* __restrict__ es2,
                         float* __restrict__ ed2) {
    __shared__ float4 Wl[1024];
    const float4* Wg4 = (const float4*)Wg2;
    for (int t = threadIdx.x; t < 1024; t += blockDim.x) Wl[t] = Wg4[t];
    int tid = blockIdx.x * blockDim.x + threadIdx.x;
    int gid = tid >> 4;
    int sl  = threadIdx.x & 15;
    __syncthreads();
    if (gid >= N_NODES) return;
    int i = nodeorder[gid];
    float4 o = gat_core(i, sl, rowptr, csr_src, es1, ed1, z1, bg1);
    int g = batch[i];
    const float4* gb4 = (const float4*)gb2;
    float4 ga = gb4[g*32 + sl];
    float4 be = gb4[g*32 + 16 + sl];
    o.x = o.x*(1.f+ga.x) + be.x;
    o.y = o.y*(1.f+ga.y) + be.y;
    o.z = o.z*(1.f+ga.z) + be.z;
    o.w = o.w*(1.f+ga.w) + be.w;
    float4 zc = rowmat16(o, sl, Wl);
    store_z_h4(z2, i, sl, zc);
    attn_proj(zc, sl, as2, ad2, i, es2, ed2);
}

__global__ void k_layer3(const int* __restrict__ nodeorder,
                         const int* __restrict__ rowptr, const int* __restrict__ csr_src,
                         const float* __restrict__ es2, const float* __restrict__ ed2,
                         const half_t* __restrict__ z2, const float* __restrict__ bg2,
                         const float* __restrict__ x,
                         const float* __restrict__ Wc1, const float* __restrict__ bc1,
                         const float* __restrict__ Wc2, const float* __restrict__ bc2,
                         const float* __restrict__ Wh1, const float* __restrict__ bh1,
                         const float* __restrict__ Wh2, const float* __restrict__ bh2,
                         float* __restrict__ out) {
    __shared__ float4 Wl[1024];
    const float4* Wc14 = (const float4*)Wc1;
    for (int t = threadIdx.x; t < 1024; t += blockDim.x) Wl[t] = Wc14[t];
    int tid = blockIdx.x * blockDim.x + threadIdx.x;
    int gid = tid >> 4;
    int sl  = threadIdx.x & 15;
    __syncthreads();
    if (gid >= N_NODES) return;
    int i = nodeorder[gid];
    float4 o = gat_core(i, sl, rowptr, csr_src, es2, ed2, z2, bg2);
    float4 acc = rowmat16(o, sl, Wl);
    float4 b4 = ((const float4*)bc1)[sl];
    acc.x = fmaxf(acc.x + b4.x, 0.f);
    acc.y = fmaxf(acc.y + b4.y, 0.f);
    acc.z = fmaxf(acc.z + b4.z, 0.f);
    acc.w = fmaxf(acc.w + b4.w, 0.f);
    const float4* Wc24 = (const float4*)Wc2;
    float4 r0 = Wc24[sl*4+0], r1 = Wc24[sl*4+1], r2 = Wc24[sl*4+2], r3 = Wc24[sl*4+3];
    float4 p;
    p.x = acc.x*r0.x + acc.y*r1.x + acc.z*r2.x + acc.w*r3.x;
    p.y = acc.x*r0.y + acc.y*r1.y + acc.z*r2.y + acc.w*r3.y;
    p.z = acc.x*r0.z + acc.y*r1.z + acc.z*r2.z + acc.w*r3.z;
    p.w = acc.x*r0.w + acc.y*r1.w + acc.z*r2.w + acc.w*r3.w;
    #pragma unroll
    for (int off = 1; off < 16; off <<= 1) {
        p.x += __shfl_xor(p.x, off, 16);
        p.y += __shfl_xor(p.y, off, 16);
        p.z += __shfl_xor(p.z, off, 16);
        p.w += __shfl_xor(p.w, off, 16);
    }
    if (sl == 0) {
        float f0 = x[i*8+6], f1 = x[i*8+7];
        float t8[8];
        #pragma unroll
        for (int q = 0; q < 8; q++)
            t8[q] = fmaxf(f0*Wh1[q] + f1*Wh1[8+q] + bh1[q], 0.f);
        float fl[4];
        #pragma unroll
        for (int q = 0; q < 4; q++) {
            float a = bh2[q];
            #pragma unroll
            for (int r = 0; r < 8; r++) a += t8[r]*Wh2[r*4+q];
            fl[q] = a;
        }
        float4 ov;
        ov.x = p.x + bc2[0] + 0.03f*fl[0];
        ov.y = p.y + bc2[1] + 0.03f*fl[1];
        ov.z = p.z + bc2[2] + 0.03f*fl[2];
        ov.w = p.w + bc2[3] + 0.03f*fl[3];
        ((float4*)out)[i] = ov;
    }
}

extern "C" void kernel_launch(void* const* d_in, const int* in_sizes, int n_in,
                              void* d_out, int out_size, void* d_ws, size_t ws_size,
                              hipStream_t stream) {
    const float* x       = (const float*)d_in[0];
    const int*   ei      = (const int*)  d_in[1];
    const int*   batch   = (const int*)  d_in[2];
    const float* climber = (const float*)d_in[3];
    const float* W_in    = (const float*)d_in[4];
    const float* b_in    = (const float*)d_in[5];
    const float* ln_g    = (const float*)d_in[6];
    const float* ln_b    = (const float*)d_in[7];
    const float* W_c     = (const float*)d_in[8];
    const float* b_c     = (const float*)d_in[9];
    const float* Wf1     = (const float*)d_in[10];
    const float* bf1     = (const float*)d_in[11];
    const float* Wf2     = (const float*)d_in[12];
    const float* bf2     = (const float*)d_in[13];
    const float* Wg1     = (const float*)d_in[14];
    const float* as1     = (const float*)d_in[15];
    const float* ad1     = (const float*)d_in[16];
    const float* bg1     = (const float*)d_in[17];
    const float* Wg2     = (const float*)d_in[18];
    const float* as2     = (const float*)d_in[19];
    const float* ad2     = (const float*)d_in[20];
    const float* bg2     = (const float*)d_in[21];
    const float* Wc1     = (const float*)d_in[22];
    const float* bc1     = (const float*)d_in[23];
    const float* Wc2     = (const float*)d_in[24];
    const float* bc2     = (const float*)d_in[25];
    const float* Wh1     = (const float*)d_in[26];
    const float* bh1     = (const float*)d_in[27];
    const float* Wh2     = (const float*)d_in[28];
    const float* bh2     = (const float*)d_in[29];
    float* out = (float*)d_out;
    float* ws  = (float*)d_ws;

    // workspace carve (floats). bucket_cnt/bucket_fill/dbin are adjacent and
    // cleared by a single memset.
    float*  gb1         = ws;                       // 128,000
    float*  gb2         = gb1 + 128000;             // 128,000
    half_t* z1          = (half_t*)(gb2 + 128000);  // 6.4M halfs
    half_t* z2          = z1 + 6400000;             // 6.4M halfs
    float*  es1         = (float*)(z2 + 6400000);   // 100,000
    float*  ed1         = es1 + N_NODES;            // 100,000
    float*  es2         = ed1 + N_NODES;            // 100,000
    float*  ed2         = es2 + N_NODES;            // 100,000
    int*    rowptr      = (int*)(ed2 + N_NODES);    // 100,001
    int*    csr_src     = rowptr + N_NODES + 1;     // 1,200,000
    int*    nodeorder   = csr_src + N_EDGES;        // 100,000
    int*    bucket_cnt  = nodeorder + N_NODES;      // 256 (memset group start)
    int*    bucket_fill = bucket_cnt + NBUCK;       // 256
    int*    dbin        = bucket_fill + NBUCK;      // 64 (memset group end)
    int*    dfill       = dbin + DBINS;             // 64 (written by k_dscan)
    int*    bucket_base = dfill + DBINS;            // 257
    int*    staged      = bucket_base + NBUCK + 1;  // 1,200,000

    // CSR build via bucket sort (topology is layer-invariant)
    hipMemsetAsync(bucket_cnt, 0, (2*NBUCK + DBINS)*sizeof(int), stream);
    k_bhist<<<S3_BLOCKS, 1024, 0, stream>>>(ei, bucket_cnt);
    k_bscan<<<1, NBUCK, 0, stream>>>(bucket_cnt, bucket_base);
    k_bin  <<<S3_BLOCKS, 1024, 0, stream>>>(ei, bucket_base, bucket_fill, staged);
    k_bcsr <<<NBUCK, 1024, 0, stream>>>(staged, bucket_base, rowptr, csr_src);

    // degree-sorted node ordering
    k_dhist   <<<NODE_BLOCKS, 256, 0, stream>>>(rowptr, dbin);
    k_dscan   <<<1, DBINS, 0, stream>>>(dbin, dfill);
    k_dscatter<<<NODE_BLOCKS, 256, 0, stream>>>(rowptr, dfill, nodeorder);

    // prologue (fused LN + FiLM coefficients)
    k_climber_film<<<N_GRAPHS, 128, 0, stream>>>(climber, ln_g, ln_b, W_c, b_c,
                                                 Wf1, bf1, Wf2, bf2, gb1, gb2);

    int nodeBlocks = (N_NODES*16 + 255)/256;   // 6250
    k_layer1<<<nodeBlocks, 256, 0, stream>>>(x, batch, W_in, b_in, gb1, Wg1,
                                             as1, ad1, z1, es1, ed1);
    k_layer2<<<nodeBlocks, 256, 0, stream>>>(nodeorder, rowptr, csr_src, es1, ed1,
                                             z1, bg1, batch, gb2, Wg2, as2, ad2,
                                             z2, es2, ed2);
    k_layer3<<<nodeBlocks, 256, 0, stream>>>(nodeorder, rowptr, csr_src, es2, ed2,
                                             z2, bg2, x, Wc1, bc1, Wc2, bc2,
                                             Wh1, bh1, Wh2, bh2, out);
}

// Round 13
// 311.422 us; speedup vs baseline: 1.0308x; 1.0308x over previous
//
#include <hip/hip_runtime.h>
#include <math.h>

#define N_NODES 100000
#define N_EDGES 1200000
#define N_GRAPHS 1000
#define HID 64
#define NBUCK 256
#define NPB   391
#define EDGE_CHUNK 16384
#define S3_BLOCKS ((N_EDGES + EDGE_CHUNK - 1) / EDGE_CHUNK)
#define LOG2E 1.4426950408889634f

typedef _Float16 half_t;
typedef __attribute__((ext_vector_type(4))) _Float16 half4;

// ---------------- CSR build via 2-level bucket sort --------------------------
// staged entry: (local_dst << 17) | src   (src < 2^17, local_dst < 512)

__global__ void k_bhist(const int* __restrict__ ei, int* __restrict__ bucket_cnt) {
    __shared__ int hist[NBUCK];
    for (int t = threadIdx.x; t < NBUCK; t += blockDim.x) hist[t] = 0;
    __syncthreads();
    int e0 = blockIdx.x * EDGE_CHUNK;
    int e1 = min(e0 + EDGE_CHUNK, N_EDGES);
    for (int e = e0 + threadIdx.x; e < e1; e += blockDim.x)
        atomicAdd(&hist[ei[N_EDGES + e] / NPB], 1);
    __syncthreads();
    for (int t = threadIdx.x; t < NBUCK; t += blockDim.x)
        if (hist[t]) atomicAdd(&bucket_cnt[t], hist[t]);
}

__global__ void k_bscan(const int* __restrict__ bucket_cnt, int* __restrict__ bucket_base) {
    __shared__ int sh[NBUCK];
    int t = threadIdx.x;
    int v = bucket_cnt[t];
    sh[t] = v;
    __syncthreads();
    for (int off = 1; off < NBUCK; off <<= 1) {
        int u = (t >= off) ? sh[t - off] : 0;
        __syncthreads();
        sh[t] += u;
        __syncthreads();
    }
    bucket_base[t] = sh[t] - v;               // exclusive
    if (t == NBUCK - 1) bucket_base[NBUCK] = sh[t];
}

__global__ void k_bin(const int* __restrict__ ei, const int* __restrict__ bucket_base,
                      int* __restrict__ bucket_fill, int* __restrict__ staged) {
    __shared__ int hist[NBUCK];
    __shared__ int cursor[NBUCK];
    for (int t = threadIdx.x; t < NBUCK; t += blockDim.x) hist[t] = 0;
    __syncthreads();
    int e0 = blockIdx.x * EDGE_CHUNK;
    int e1 = min(e0 + EDGE_CHUNK, N_EDGES);
    for (int e = e0 + threadIdx.x; e < e1; e += blockDim.x)
        atomicAdd(&hist[ei[N_EDGES + e] / NPB], 1);
    __syncthreads();
    if (threadIdx.x < NBUCK) {
        int hv = hist[threadIdx.x];
        int start = bucket_base[threadIdx.x];
        if (hv) start += atomicAdd(&bucket_fill[threadIdx.x], hv);
        cursor[threadIdx.x] = start;
    }
    __syncthreads();
    for (int e = e0 + threadIdx.x; e < e1; e += blockDim.x) {
        int src = ei[e], dst = ei[N_EDGES + e];
        int b = dst / NPB;
        int ldst = dst - b * NPB;
        int pos = atomicAdd(&cursor[b], 1);
        staged[pos] = (ldst << 17) | src;
    }
}

__global__ void k_bcsr(const int* __restrict__ staged, const int* __restrict__ bucket_base,
                       int* __restrict__ rowptr, int* __restrict__ csr_src) {
    __shared__ int ldeg[NPB];
    __shared__ int sc[512];
    __shared__ int cursor[NPB];
    int b = blockIdx.x;
    int n0 = b * NPB;
    int n1 = min(n0 + NPB, N_NODES);
    int nn = n1 - n0;
    int bbase = bucket_base[b];
    int bcnt  = bucket_base[b+1] - bbase;
    for (int t = threadIdx.x; t < NPB; t += blockDim.x) ldeg[t] = 0;
    __syncthreads();
    for (int k = threadIdx.x; k < bcnt; k += blockDim.x)
        atomicAdd(&ldeg[staged[bbase + k] >> 17], 1);
    __syncthreads();
    if (threadIdx.x < 512) sc[threadIdx.x] = (threadIdx.x < nn) ? ldeg[threadIdx.x] : 0;
    __syncthreads();
    for (int off = 1; off < 512; off <<= 1) {
        int u = 0;
        if (threadIdx.x < 512 && threadIdx.x >= off) u = sc[threadIdx.x - off];
        __syncthreads();
        if (threadIdx.x < 512) sc[threadIdx.x] += u;
        __syncthreads();
    }
    if (threadIdx.x < nn) {
        int pre = sc[threadIdx.x] - ldeg[threadIdx.x];     // exclusive
        rowptr[n0 + threadIdx.x] = bbase + pre;
        cursor[threadIdx.x] = bbase + pre;
    }
    if (b == 0 && threadIdx.x == 0) rowptr[N_NODES] = bucket_base[NBUCK];
    __syncthreads();
    for (int k = threadIdx.x; k < bcnt; k += blockDim.x) {
        int v = staged[bbase + k];
        int pos = atomicAdd(&cursor[v >> 17], 1);
        csr_src[pos] = v & 0x1FFFF;
    }
}

// ---------------- fused climber LN + FiLM coefficient kernel -----------------
__global__ void k_climber_film(const float* __restrict__ climber,
                               const float* __restrict__ ln_g, const float* __restrict__ ln_b,
                               const float* __restrict__ W_c, const float* __restrict__ b_c,
                               const float* __restrict__ Wf1, const float* __restrict__ bf1,
                               const float* __restrict__ Wf2, const float* __restrict__ bf2,
                               float* __restrict__ gb1, float* __restrict__ gb2) {
    __shared__ float cl[64];
    int g = blockIdx.x;
    int j = threadIdx.x;
    if (j < 64) {
        float v[6];
        float mu = 0.f;
        #pragma unroll
        for (int k = 0; k < 6; k++) { v[k] = climber[g*6+k]; mu += v[k]; }
        mu *= (1.f/6.f);
        float var = 0.f;
        #pragma unroll
        for (int k = 0; k < 6; k++) { float d = v[k]-mu; var += d*d; }
        var *= (1.f/6.f);
        float rs = rsqrtf(var + 1e-5f);
        float acc = b_c[j];
        #pragma unroll
        for (int k = 0; k < 6; k++) {
            float cn = (v[k]-mu)*rs*ln_g[k] + ln_b[k];
            acc += cn * W_c[k*64+j];
        }
        cl[j] = fmaxf(acc, 0.f);
    }
    __syncthreads();
    float a1 = bf1[j], a2 = bf2[j];
    #pragma unroll 8
    for (int k = 0; k < 64; k++) {
        float ck = cl[k];
        a1 += ck * Wf1[k*128+j];
        a2 += ck * Wf2[k*128+j];
    }
    gb1[g*128+j] = a1;
    gb2[g*128+j] = a2;
}

// ---------------- fused node kernels ----------------------------------------
// Layout: 4 nodes per wave, 16 lanes/node, lane sl holds features 4sl..4sl+3.
// z fp16; es/ed pre-scaled by log2(e). NO segment-max: scores are bounded
// (|score| < ~30), exp2 never overflows fp32; alpha = e_k/sum(e) identical.
// Edge exps computed LANE-PARALLEL (16 per VALU op), then shuffled.

__device__ __forceinline__ float4 h4_to_f4(half4 h) {
    float4 f;
    f.x = (float)h.x; f.y = (float)h.y; f.z = (float)h.z; f.w = (float)h.w;
    return f;
}

__device__ __forceinline__ float4 gat_core(int i, int sl,
    const int* __restrict__ rowptr, const int* __restrict__ csr_src,
    const float* __restrict__ es, const float* __restrict__ ed,
    const half_t* __restrict__ z, const float* __restrict__ bg) {
    int beg = rowptr[i], end = rowptr[i+1];
    int deg = end - beg;
    float edi = ed[i];

    float e_self = es[i] + edi;
    e_self = fmaxf(e_self, 0.2f * e_self);

    // lane-parallel: load up to 32 edges, compute leaky+exp2 in 2 VALU ops
    int svA = 0, svB = 0;
    float exA = 0.f, exB = 0.f;
    if (sl < deg) {
        svA = csr_src[beg + sl];
        float v = es[svA] + edi;
        exA = exp2f(fmaxf(v, 0.2f * v));
    }
    if (16 + sl < deg) {
        svB = csr_src[beg + 16 + sl];
        float v = es[svB] + edi;
        exB = exp2f(fmaxf(v, 0.2f * v));
    }

    // softmax denominator: reduce over the 16-lane group (+ tail later)
    float s = exA + exB;
    #pragma unroll
    for (int off = 1; off < 16; off <<= 1)
        s += __shfl_xor(s, off, 16);
    float ex = exp2f(e_self);
    s += ex;

    const half4* z4 = (const half4*)z;
    float4 zi = h4_to_f4(z4[i*16 + sl]);
    float4 acc = {ex*zi.x, ex*zi.y, ex*zi.z, ex*zi.w};

    int lim = (deg < 32) ? deg : 32;
    int k = 0;
    for (; k + 8 <= lim; k += 8) {
        int a[8]; float e[8];
        if (k < 16) {
            #pragma unroll
            for (int j = 0; j < 8; j++) {
                a[j] = __shfl(svA, k+j, 16);
                e[j] = __shfl(exA, k+j, 16);
            }
        } else {
            #pragma unroll
            for (int j = 0; j < 8; j++) {
                a[j] = __shfl(svB, k-16+j, 16);
                e[j] = __shfl(exB, k-16+j, 16);
            }
        }
        half4 q[8];
        #pragma unroll
        for (int j = 0; j < 8; j++) q[j] = z4[a[j]*16 + sl];
        #pragma unroll
        for (int j = 0; j < 8; j++) {
            float4 r = h4_to_f4(q[j]);
            acc.x += e[j]*r.x; acc.y += e[j]*r.y;
            acc.z += e[j]*r.z; acc.w += e[j]*r.w;
        }
    }
    for (; k + 4 <= lim; k += 4) {
        int a[4]; float e[4];
        if (k < 16) {
            #pragma unroll
            for (int j = 0; j < 4; j++) {
                a[j] = __shfl(svA, k+j, 16);
                e[j] = __shfl(exA, k+j, 16);
            }
        } else {
            #pragma unroll
            for (int j = 0; j < 4; j++) {
                a[j] = __shfl(svB, k-16+j, 16);
                e[j] = __shfl(exB, k-16+j, 16);
            }
        }
        half4 q[4];
        #pragma unroll
        for (int j = 0; j < 4; j++) q[j] = z4[a[j]*16 + sl];
        #pragma unroll
        for (int j = 0; j < 4; j++) {
            float4 r = h4_to_f4(q[j]);
            acc.x += e[j]*r.x; acc.y += e[j]*r.y;
            acc.z += e[j]*r.z; acc.w += e[j]*r.w;
        }
    }
    for (; k < lim; k++) {
        int a; float e2;
        if (k < 16) { a = __shfl(svA, k, 16);    e2 = __shfl(exA, k, 16); }
        else        { a = __shfl(svB, k-16, 16); e2 = __shfl(exB, k-16, 16); }
        float4 zr = h4_to_f4(z4[a*16 + sl]);
        acc.x += e2*zr.x; acc.y += e2*zr.y; acc.z += e2*zr.z; acc.w += e2*zr.w;
    }
    for (int kk = beg + 32; kk < end; kk++) {   // rare: deg > 32
        int sv = csr_src[kk];
        float v = es[sv] + edi;
        float e2 = exp2f(fmaxf(v, 0.2f * v));
        s += e2;
        float4 zr = h4_to_f4(z4[sv*16 + sl]);
        acc.x += e2*zr.x; acc.y += e2*zr.y; acc.z += e2*zr.z; acc.w += e2*zr.w;
    }
    float inv = 1.f / (s + 1e-16f);
    float4 bg4 = ((const float4*)bg)[sl];
    float4 o;
    o.x = fmaxf(acc.x*inv + bg4.x, 0.f);
    o.y = fmaxf(acc.y*inv + bg4.y, 0.f);
    o.z = fmaxf(acc.z*inv + bg4.z, 0.f);
    o.w = fmaxf(acc.w*inv + bg4.w, 0.f);
    return o;
}

__device__ __forceinline__ float4 rowmat16(float4 hr, int sl, const float4* Wl) {
    float hv[4] = {hr.x, hr.y, hr.z, hr.w};
    float4 acc = {0.f, 0.f, 0.f, 0.f};
    #pragma unroll
    for (int k = 0; k < 64; k++) {
        float hk = __shfl(hv[k & 3], k >> 2, 16);
        float4 w = Wl[k*16 + sl];
        acc.x += hk*w.x; acc.y += hk*w.y; acc.z += hk*w.z; acc.w += hk*w.w;
    }
    return acc;
}

// stores es/ed PRE-SCALED by log2(e)
__device__ __forceinline__ void attn_proj(float4 zc, int sl,
    const float* __restrict__ a_src, const float* __restrict__ a_dst,
    int i, float* __restrict__ es, float* __restrict__ ed) {
    float4 as4 = ((const float4*)a_src)[sl];
    float4 ad4 = ((const float4*)a_dst)[sl];
    float ps = zc.x*as4.x + zc.y*as4.y + zc.z*as4.z + zc.w*as4.w;
    float pd = zc.x*ad4.x + zc.y*ad4.y + zc.z*ad4.z + zc.w*ad4.w;
    #pragma unroll
    for (int off = 1; off < 16; off <<= 1) {
        ps += __shfl_xor(ps, off, 16);
        pd += __shfl_xor(pd, off, 16);
    }
    if (sl == 0) { es[i] = ps * LOG2E; ed[i] = pd * LOG2E; }
}

__device__ __forceinline__ void store_z_h4(half_t* z, int i, int sl, float4 zc) {
    half4 h;
    h.x = (half_t)zc.x; h.y = (half_t)zc.y; h.z = (half_t)zc.z; h.w = (half_t)zc.w;
    ((half4*)z)[i*16 + sl] = h;
}

__global__ void k_layer1(const float* __restrict__ x, const int* __restrict__ batch,
                         const float* __restrict__ W_in, const float* __restrict__ b_in,
                         const float* __restrict__ gb1, const float* __restrict__ Wg1,
                         const float* __restrict__ as1, const float* __restrict__ ad1,
                         half_t* __restrict__ z1, float* __restrict__ es1,
                         float* __restrict__ ed1) {
    __shared__ float4 Wl[1024];
    const float4* Wg4 = (const float4*)Wg1;
    for (int t = threadIdx.x; t < 1024; t += blockDim.x) Wl[t] = Wg4[t];
    int tid = blockIdx.x * blockDim.x + threadIdx.x;
    int i  = tid >> 4;
    int sl = threadIdx.x & 15;
    __syncthreads();
    if (i >= N_NODES) return;
    float4 acc = ((const float4*)b_in)[sl];
    #pragma unroll
    for (int k = 0; k < 6; k++) {
        float xk = x[i*8+k];
        float4 w = ((const float4*)W_in)[k*16 + sl];
        acc.x += xk*w.x; acc.y += xk*w.y; acc.z += xk*w.z; acc.w += xk*w.w;
    }
    int g = batch[i];
    const float4* gb4 = (const float4*)gb1;
    float4 ga = gb4[g*32 + sl];
    float4 be = gb4[g*32 + 16 + sl];
    acc.x = acc.x*(1.f+ga.x) + be.x;
    acc.y = acc.y*(1.f+ga.y) + be.y;
    acc.z = acc.z*(1.f+ga.z) + be.z;
    acc.w = acc.w*(1.f+ga.w) + be.w;
    float4 zc = rowmat16(acc, sl, Wl);
    store_z_h4(z1, i, sl, zc);
    attn_proj(zc, sl, as1, ad1, i, es1, ed1);
}

__global__ void k_layer2(const int* __restrict__ rowptr, const int* __restrict__ csr_src,
                         const float* __restrict__ es1, const float* __restrict__ ed1,
                         const half_t* __restrict__ z1, const float* __restrict__ bg1,
                         const int* __restrict__ batch, const float* __restrict__ gb2,
                         const float* __restrict__ Wg2, const float* __restrict__ as2,
                         const float* __restrict__ ad2,
                         half_t* __restrict__ z2, float* __restrict__ es2,
                         float* __restrict__ ed2) {
    __shared__ float4 Wl[1024];
    const float4* Wg4 = (const float4*)Wg2;
    for (int t = threadIdx.x; t < 1024; t += blockDim.x) Wl[t] = Wg4[t];
    int tid = blockIdx.x * blockDim.x + threadIdx.x;
    int i  = tid >> 4;
    int sl = threadIdx.x & 15;
    __syncthreads();
    if (i >= N_NODES) return;
    float4 o = gat_core(i, sl, rowptr, csr_src, es1, ed1, z1, bg1);
    int g = batch[i];
    const float4* gb4 = (const float4*)gb2;
    float4 ga = gb4[g*32 + sl];
    float4 be = gb4[g*32 + 16 + sl];
    o.x = o.x*(1.f+ga.x) + be.x;
    o.y = o.y*(1.f+ga.y) + be.y;
    o.z = o.z*(1.f+ga.z) + be.z;
    o.w = o.w*(1.f+ga.w) + be.w;
    float4 zc = rowmat16(o, sl, Wl);
    store_z_h4(z2, i, sl, zc);
    attn_proj(zc, sl, as2, ad2, i, es2, ed2);
}

__global__ void k_layer3(const int* __restrict__ rowptr, const int* __restrict__ csr_src,
                         const float* __restrict__ es2, const float* __restrict__ ed2,
                         const half_t* __restrict__ z2, const float* __restrict__ bg2,
                         const float* __restrict__ x,
                         const float* __restrict__ Wc1, const float* __restrict__ bc1,
                         const float* __restrict__ Wc2, const float* __restrict__ bc2,
                         const float* __restrict__ Wh1, const float* __restrict__ bh1,
                         const float* __restrict__ Wh2, const float* __restrict__ bh2,
                         float* __restrict__ out) {
    __shared__ float4 Wl[1024];
    const float4* Wc14 = (const float4*)Wc1;
    for (int t = threadIdx.x; t < 1024; t += blockDim.x) Wl[t] = Wc14[t];
    int tid = blockIdx.x * blockDim.x + threadIdx.x;
    int i  = tid >> 4;
    int sl = threadIdx.x & 15;
    __syncthreads();
    if (i >= N_NODES) return;
    float4 o = gat_core(i, sl, rowptr, csr_src, es2, ed2, z2, bg2);
    float4 acc = rowmat16(o, sl, Wl);
    float4 b4 = ((const float4*)bc1)[sl];
    acc.x = fmaxf(acc.x + b4.x, 0.f);
    acc.y = fmaxf(acc.y + b4.y, 0.f);
    acc.z = fmaxf(acc.z + b4.z, 0.f);
    acc.w = fmaxf(acc.w + b4.w, 0.f);
    const float4* Wc24 = (const float4*)Wc2;
    float4 r0 = Wc24[sl*4+0], r1 = Wc24[sl*4+1], r2 = Wc24[sl*4+2], r3 = Wc24[sl*4+3];
    float4 p;
    p.x = acc.x*r0.x + acc.y*r1.x + acc.z*r2.x + acc.w*r3.x;
    p.y = acc.x*r0.y + acc.y*r1.y + acc.z*r2.y + acc.w*r3.y;
    p.z = acc.x*r0.z + acc.y*r1.z + acc.z*r2.z + acc.w*r3.z;
    p.w = acc.x*r0.w + acc.y*r1.w + acc.z*r2.w + acc.w*r3.w;
    #pragma unroll
    for (int off = 1; off < 16; off <<= 1) {
        p.x += __shfl_xor(p.x, off, 16);
        p.y += __shfl_xor(p.y, off, 16);
        p.z += __shfl_xor(p.z, off, 16);
        p.w += __shfl_xor(p.w, off, 16);
    }
    if (sl == 0) {
        float f0 = x[i*8+6], f1 = x[i*8+7];
        float t8[8];
        #pragma unroll
        for (int q = 0; q < 8; q++)
            t8[q] = fmaxf(f0*Wh1[q] + f1*Wh1[8+q] + bh1[q], 0.f);
        float fl[4];
        #pragma unroll
        for (int q = 0; q < 4; q++) {
            float a = bh2[q];
            #pragma unroll
            for (int r = 0; r < 8; r++) a += t8[r]*Wh2[r*4+q];
            fl[q] = a;
        }
        float4 ov;
        ov.x = p.x + bc2[0] + 0.03f*fl[0];
        ov.y = p.y + bc2[1] + 0.03f*fl[1];
        ov.z = p.z + bc2[2] + 0.03f*fl[2];
        ov.w = p.w + bc2[3] + 0.03f*fl[3];
        ((float4*)out)[i] = ov;
    }
}

extern "C" void kernel_launch(void* const* d_in, const int* in_sizes, int n_in,
                              void* d_out, int out_size, void* d_ws, size_t ws_size,
                              hipStream_t stream) {
    const float* x       = (const float*)d_in[0];
    const int*   ei      = (const int*)  d_in[1];
    const int*   batch   = (const int*)  d_in[2];
    const float* climber = (const float*)d_in[3];
    const float* W_in    = (const float*)d_in[4];
    const float* b_in    = (const float*)d_in[5];
    const float* ln_g    = (const float*)d_in[6];
    const float* ln_b    = (const float*)d_in[7];
    const float* W_c     = (const float*)d_in[8];
    const float* b_c     = (const float*)d_in[9];
    const float* Wf1     = (const float*)d_in[10];
    const float* bf1     = (const float*)d_in[11];
    const float* Wf2     = (const float*)d_in[12];
    const float* bf2     = (const float*)d_in[13];
    const float* Wg1     = (const float*)d_in[14];
    const float* as1     = (const float*)d_in[15];
    const float* ad1     = (const float*)d_in[16];
    const float* bg1     = (const float*)d_in[17];
    const float* Wg2     = (const float*)d_in[18];
    const float* as2     = (const float*)d_in[19];
    const float* ad2     = (const float*)d_in[20];
    const float* bg2     = (const float*)d_in[21];
    const float* Wc1     = (const float*)d_in[22];
    const float* bc1     = (const float*)d_in[23];
    const float* Wc2     = (const float*)d_in[24];
    const float* bc2     = (const float*)d_in[25];
    const float* Wh1     = (const float*)d_in[26];
    const float* bh1     = (const float*)d_in[27];
    const float* Wh2     = (const float*)d_in[28];
    const float* bh2     = (const float*)d_in[29];
    float* out = (float*)d_out;
    float* ws  = (float*)d_ws;

    // workspace carve (floats); bucket_cnt and bucket_fill adjacent -> one memset
    float*  gb1         = ws;                       // 128,000
    float*  gb2         = gb1 + 128000;             // 128,000
    half_t* z1          = (half_t*)(gb2 + 128000);  // 6.4M halfs
    half_t* z2          = z1 + 6400000;             // 6.4M halfs
    float*  es1         = (float*)(z2 + 6400000);   // 100,000
    float*  ed1         = es1 + N_NODES;            // 100,000
    float*  es2         = ed1 + N_NODES;            // 100,000
    float*  ed2         = es2 + N_NODES;            // 100,000
    int*    rowptr      = (int*)(ed2 + N_NODES);    // 100,001
    int*    csr_src     = rowptr + N_NODES + 1;     // 1,200,000
    int*    bucket_cnt  = csr_src + N_EDGES;        // 256 (memset start)
    int*    bucket_fill = bucket_cnt + NBUCK;       // 256 (memset end)
    int*    bucket_base = bucket_fill + NBUCK;      // 257
    int*    staged      = bucket_base + NBUCK + 1;  // 1,200,000

    // CSR build via bucket sort (topology is layer-invariant)
    hipMemsetAsync(bucket_cnt, 0, 2*NBUCK*sizeof(int), stream);
    k_bhist<<<S3_BLOCKS, 1024, 0, stream>>>(ei, bucket_cnt);
    k_bscan<<<1, NBUCK, 0, stream>>>(bucket_cnt, bucket_base);
    k_bin  <<<S3_BLOCKS, 1024, 0, stream>>>(ei, bucket_base, bucket_fill, staged);
    k_bcsr <<<NBUCK, 1024, 0, stream>>>(staged, bucket_base, rowptr, csr_src);

    // prologue (fused LN + FiLM coefficients)
    k_climber_film<<<N_GRAPHS, 128, 0, stream>>>(climber, ln_g, ln_b, W_c, b_c,
                                                 Wf1, bf1, Wf2, bf2, gb1, gb2);

    int nodeBlocks = (N_NODES*16 + 255)/256;   // 6250
    k_layer1<<<nodeBlocks, 256, 0, stream>>>(x, batch, W_in, b_in, gb1, Wg1,
                                             as1, ad1, z1, es1, ed1);
    k_layer2<<<nodeBlocks, 256, 0, stream>>>(rowptr, csr_src, es1, ed1, z1, bg1,
                                             batch, gb2, Wg2, as2, ad2, z2, es2, ed2);
    k_layer3<<<nodeBlocks, 256, 0, stream>>>(rowptr, csr_src, es2, ed2, z2, bg2,
                                             x, Wc1, bc1, Wc2, bc2,
                                             Wh1, bh1, Wh2, bh2, out);
}

// Round 14
// 279.045 us; speedup vs baseline: 1.1504x; 1.1160x over previous
//
#include <hip/hip_runtime.h>
#include <math.h>

#define N_NODES 100000
#define N_EDGES 1200000
#define N_GRAPHS 1000
#define HID 64
#define NBUCK 256
#define NPB   391
#define EDGE_CHUNK 16384
#define S3_BLOCKS ((N_EDGES + EDGE_CHUNK - 1) / EDGE_CHUNK)
#define LOG2E 1.4426950408889634f
#define N_TILES (N_NODES / 16)      // 6250, exact
#define MFMA_BLOCKS 391

typedef _Float16 half_t;
typedef __attribute__((ext_vector_type(4))) _Float16 half4;
typedef __attribute__((ext_vector_type(8))) _Float16 half8;
typedef __attribute__((ext_vector_type(4))) float floatx4;

// ---------------- CSR build via 2-level bucket sort --------------------------
// staged entry: (local_dst << 17) | src   (src < 2^17, local_dst < 512)

__global__ void k_bhist(const int* __restrict__ ei, int* __restrict__ bucket_cnt) {
    __shared__ int hist[NBUCK];
    for (int t = threadIdx.x; t < NBUCK; t += blockDim.x) hist[t] = 0;
    __syncthreads();
    int e0 = blockIdx.x * EDGE_CHUNK;
    int e1 = min(e0 + EDGE_CHUNK, N_EDGES);
    for (int e = e0 + threadIdx.x; e < e1; e += blockDim.x)
        atomicAdd(&hist[ei[N_EDGES + e] / NPB], 1);
    __syncthreads();
    for (int t = threadIdx.x; t < NBUCK; t += blockDim.x)
        if (hist[t]) atomicAdd(&bucket_cnt[t], hist[t]);
}

__global__ void k_bscan(const int* __restrict__ bucket_cnt, int* __restrict__ bucket_base) {
    __shared__ int sh[NBUCK];
    int t = threadIdx.x;
    int v = bucket_cnt[t];
    sh[t] = v;
    __syncthreads();
    for (int off = 1; off < NBUCK; off <<= 1) {
        int u = (t >= off) ? sh[t - off] : 0;
        __syncthreads();
        sh[t] += u;
        __syncthreads();
    }
    bucket_base[t] = sh[t] - v;               // exclusive
    if (t == NBUCK - 1) bucket_base[NBUCK] = sh[t];
}

__global__ void k_bin(const int* __restrict__ ei, const int* __restrict__ bucket_base,
                      int* __restrict__ bucket_fill, int* __restrict__ staged) {
    __shared__ int hist[NBUCK];
    __shared__ int cursor[NBUCK];
    for (int t = threadIdx.x; t < NBUCK; t += blockDim.x) hist[t] = 0;
    __syncthreads();
    int e0 = blockIdx.x * EDGE_CHUNK;
    int e1 = min(e0 + EDGE_CHUNK, N_EDGES);
    for (int e = e0 + threadIdx.x; e < e1; e += blockDim.x)
        atomicAdd(&hist[ei[N_EDGES + e] / NPB], 1);
    __syncthreads();
    if (threadIdx.x < NBUCK) {
        int hv = hist[threadIdx.x];
        int start = bucket_base[threadIdx.x];
        if (hv) start += atomicAdd(&bucket_fill[threadIdx.x], hv);
        cursor[threadIdx.x] = start;
    }
    __syncthreads();
    for (int e = e0 + threadIdx.x; e < e1; e += blockDim.x) {
        int src = ei[e], dst = ei[N_EDGES + e];
        int b = dst / NPB;
        int ldst = dst - b * NPB;
        int pos = atomicAdd(&cursor[b], 1);
        staged[pos] = (ldst << 17) | src;
    }
}

__global__ void k_bcsr(const int* __restrict__ staged, const int* __restrict__ bucket_base,
                       int* __restrict__ rowptr, int* __restrict__ csr_src) {
    __shared__ int ldeg[NPB];
    __shared__ int sc[512];
    __shared__ int cursor[NPB];
    int b = blockIdx.x;
    int n0 = b * NPB;
    int n1 = min(n0 + NPB, N_NODES);
    int nn = n1 - n0;
    int bbase = bucket_base[b];
    int bcnt  = bucket_base[b+1] - bbase;
    for (int t = threadIdx.x; t < NPB; t += blockDim.x) ldeg[t] = 0;
    __syncthreads();
    for (int k = threadIdx.x; k < bcnt; k += blockDim.x)
        atomicAdd(&ldeg[staged[bbase + k] >> 17], 1);
    __syncthreads();
    if (threadIdx.x < 512) sc[threadIdx.x] = (threadIdx.x < nn) ? ldeg[threadIdx.x] : 0;
    __syncthreads();
    for (int off = 1; off < 512; off <<= 1) {
        int u = 0;
        if (threadIdx.x < 512 && threadIdx.x >= off) u = sc[threadIdx.x - off];
        __syncthreads();
        if (threadIdx.x < 512) sc[threadIdx.x] += u;
        __syncthreads();
    }
    if (threadIdx.x < nn) {
        int pre = sc[threadIdx.x] - ldeg[threadIdx.x];     // exclusive
        rowptr[n0 + threadIdx.x] = bbase + pre;
        cursor[threadIdx.x] = bbase + pre;
    }
    if (b == 0 && threadIdx.x == 0) rowptr[N_NODES] = bucket_base[NBUCK];
    __syncthreads();
    for (int k = threadIdx.x; k < bcnt; k += blockDim.x) {
        int v = staged[bbase + k];
        int pos = atomicAdd(&cursor[v >> 17], 1);
        csr_src[pos] = v & 0x1FFFF;
    }
}

// ---------------- fused climber LN + FiLM coefficient kernel -----------------
__global__ void k_climber_film(const float* __restrict__ climber,
                               const float* __restrict__ ln_g, const float* __restrict__ ln_b,
                               const float* __restrict__ W_c, const float* __restrict__ b_c,
                               const float* __restrict__ Wf1, const float* __restrict__ bf1,
                               const float* __restrict__ Wf2, const float* __restrict__ bf2,
                               float* __restrict__ gb1, float* __restrict__ gb2) {
    __shared__ float cl[64];
    int g = blockIdx.x;
    int j = threadIdx.x;
    if (j < 64) {
        float v[6];
        float mu = 0.f;
        #pragma unroll
        for (int k = 0; k < 6; k++) { v[k] = climber[g*6+k]; mu += v[k]; }
        mu *= (1.f/6.f);
        float var = 0.f;
        #pragma unroll
        for (int k = 0; k < 6; k++) { float d = v[k]-mu; var += d*d; }
        var *= (1.f/6.f);
        float rs = rsqrtf(var + 1e-5f);
        float acc = b_c[j];
        #pragma unroll
        for (int k = 0; k < 6; k++) {
            float cn = (v[k]-mu)*rs*ln_g[k] + ln_b[k];
            acc += cn * W_c[k*64+j];
        }
        cl[j] = fmaxf(acc, 0.f);
    }
    __syncthreads();
    float a1 = bf1[j], a2 = bf2[j];
    #pragma unroll 8
    for (int k = 0; k < 64; k++) {
        float ck = cl[k];
        a1 += ck * Wf1[k*128+j];
        a2 += ck * Wf2[k*128+j];
    }
    gb1[g*128+j] = a1;
    gb2[g*128+j] = a2;
}

// ---------------- node init: h1 = film1(x@W_in + b_in), fp16 ----------------
__global__ void k_node0(const float* __restrict__ x, const int* __restrict__ batch,
                        const float* __restrict__ W_in, const float* __restrict__ b_in,
                        const float* __restrict__ gb1, half_t* __restrict__ h) {
    int tid = blockIdx.x * blockDim.x + threadIdx.x;
    int i  = tid >> 4;
    int sl = threadIdx.x & 15;
    if (i >= N_NODES) return;
    float4 acc = ((const float4*)b_in)[sl];
    #pragma unroll
    for (int k = 0; k < 6; k++) {
        float xk = x[i*8+k];
        float4 w = ((const float4*)W_in)[k*16 + sl];
        acc.x += xk*w.x; acc.y += xk*w.y; acc.z += xk*w.z; acc.w += xk*w.w;
    }
    int g = batch[i];
    const float4* gb4 = (const float4*)gb1;
    float4 ga = gb4[g*32 + sl];
    float4 be = gb4[g*32 + 16 + sl];
    half4 hv;
    hv.x = (half_t)(acc.x*(1.f+ga.x) + be.x);
    hv.y = (half_t)(acc.y*(1.f+ga.y) + be.y);
    hv.z = (half_t)(acc.z*(1.f+ga.z) + be.z);
    hv.w = (half_t)(acc.w*(1.f+ga.w) + be.w);
    ((half4*)h)[i*16 + sl] = hv;
}

// ---------------- MFMA transform: z = h @ W (fp16 in, fp32 acc) -------------
// 16-node tiles. A: row=lane&15, k=(lane>>4)*8+j.  B: col=lane&15, same k.
// D (verified layout): col=lane&15, row=(lane>>4)*4+reg.
// Also emits es = z@a_src * LOG2E, ed = z@a_dst * LOG2E from fp32 D frags.
__global__ __launch_bounds__(256) void k_mfma_z(
        const half_t* __restrict__ h, const float* __restrict__ W,
        const float* __restrict__ a_src, const float* __restrict__ a_dst,
        half_t* __restrict__ z, float* __restrict__ es, float* __restrict__ ed) {
    __shared__ half_t zl[4][16*64];          // per-wave 2 KB transpose staging
    int wave = threadIdx.x >> 6;
    int l    = threadIdx.x & 63;
    int c    = l & 15;
    int g    = l >> 4;
    // B fragments (held in VGPRs for all tiles): B[k][n], k=ko*32+g*8+j, n=c+16*nt
    half8 Bf[2][4];
    #pragma unroll
    for (int ko = 0; ko < 2; ko++) {
        #pragma unroll
        for (int nt = 0; nt < 4; nt++) {
            half8 b;
            #pragma unroll
            for (int j = 0; j < 8; j++)
                b[j] = (half_t)W[(ko*32 + g*8 + j)*64 + c + 16*nt];
            Bf[ko][nt] = b;
        }
    }
    float as4[4], ad4[4];
    #pragma unroll
    for (int nt = 0; nt < 4; nt++) {
        as4[nt] = a_src[c + 16*nt] * LOG2E;
        ad4[nt] = a_dst[c + 16*nt] * LOG2E;
    }
    int nWaves = gridDim.x * 4;
    int wid = blockIdx.x * 4 + wave;
    half_t* zw = zl[wave];
    for (int t = wid; t < N_TILES; t += nWaves) {
        int m0 = t * 16;
        const half8* hrow = (const half8*)(h + (size_t)(m0 + c) * 64);
        half8 A0 = hrow[g];          // k 0..31 slice for this lane
        half8 A1 = hrow[g + 4];      // k 32..63
        floatx4 D[4];
        #pragma unroll
        for (int nt = 0; nt < 4; nt++) {
            floatx4 acc = {0.f, 0.f, 0.f, 0.f};
            acc = __builtin_amdgcn_mfma_f32_16x16x32_f16(A0, Bf[0][nt], acc, 0, 0, 0);
            acc = __builtin_amdgcn_mfma_f32_16x16x32_f16(A1, Bf[1][nt], acc, 0, 0, 0);
            D[nt] = acc;
        }
        // es/ed: row m0+g*4+r spread over lanes c=0..15
        #pragma unroll
        for (int r = 0; r < 4; r++) {
            float ps = D[0][r]*as4[0] + D[1][r]*as4[1] + D[2][r]*as4[2] + D[3][r]*as4[3];
            float pd = D[0][r]*ad4[0] + D[1][r]*ad4[1] + D[2][r]*ad4[2] + D[3][r]*ad4[3];
            #pragma unroll
            for (int off = 1; off < 16; off <<= 1) {
                ps += __shfl_xor(ps, off, 16);
                pd += __shfl_xor(pd, off, 16);
            }
            if (c == 0) {
                es[m0 + g*4 + r] = ps;
                ed[m0 + g*4 + r] = pd;
            }
        }
        // transpose D -> row-major z via wave-private LDS, then coalesced store
        #pragma unroll
        for (int nt = 0; nt < 4; nt++) {
            #pragma unroll
            for (int r = 0; r < 4; r++)
                zw[(g*4 + r)*64 + c + 16*nt] = (half_t)D[nt][r];
        }
        __asm__ __volatile__("s_waitcnt lgkmcnt(0)" ::: "memory");
        const half8* zr = (const half8*)zw;
        half8 v0 = zr[l*2];
        half8 v1 = zr[l*2 + 1];
        half8* zo = (half8*)(z + (size_t)m0 * 64);
        zo[l*2]     = v0;
        zo[l*2 + 1] = v1;
        __asm__ __volatile__("s_waitcnt lgkmcnt(0)" ::: "memory");
    }
}

// ---------------- gather/softmax aggregation (no transform) ------------------
// 4 nodes/wave, 16 lanes/node. z fp16; es/ed pre-scaled by log2(e); no max
// (scores bounded, exp2 safe in fp32; alpha = e_k/sum identical).
__device__ __forceinline__ float4 h4_to_f4(half4 h) {
    float4 f;
    f.x = (float)h.x; f.y = (float)h.y; f.z = (float)h.z; f.w = (float)h.w;
    return f;
}

__global__ void k_agg(const int* __restrict__ rowptr, const int* __restrict__ csr_src,
                      const float* __restrict__ es, const float* __restrict__ ed,
                      const half_t* __restrict__ z, const float* __restrict__ bg,
                      const int* __restrict__ batch, const float* __restrict__ gb,
                      int apply_film, half_t* __restrict__ hout) {
    int tid = blockIdx.x * blockDim.x + threadIdx.x;
    int i  = tid >> 4;
    int sl = threadIdx.x & 15;
    if (i >= N_NODES) return;
    int beg = rowptr[i], end = rowptr[i+1];
    int deg = end - beg;
    float edi = ed[i];

    float e_self = es[i] + edi;
    e_self = fmaxf(e_self, 0.2f * e_self);

    int svA = 0, svB = 0;
    float exA = 0.f, exB = 0.f;
    if (sl < deg) {
        svA = csr_src[beg + sl];
        float v = es[svA] + edi;
        exA = exp2f(fmaxf(v, 0.2f * v));
    }
    if (16 + sl < deg) {
        svB = csr_src[beg + 16 + sl];
        float v = es[svB] + edi;
        exB = exp2f(fmaxf(v, 0.2f * v));
    }
    float s = exA + exB;
    #pragma unroll
    for (int off = 1; off < 16; off <<= 1)
        s += __shfl_xor(s, off, 16);
    float ex = exp2f(e_self);
    s += ex;

    const half4* z4 = (const half4*)z;
    float4 zi = h4_to_f4(z4[i*16 + sl]);
    float4 acc = {ex*zi.x, ex*zi.y, ex*zi.z, ex*zi.w};

    int lim = (deg < 32) ? deg : 32;
    int k = 0;
    for (; k + 8 <= lim; k += 8) {
        int a[8]; float e[8];
        if (k < 16) {
            #pragma unroll
            for (int j = 0; j < 8; j++) {
                a[j] = __shfl(svA, k+j, 16);
                e[j] = __shfl(exA, k+j, 16);
            }
        } else {
            #pragma unroll
            for (int j = 0; j < 8; j++) {
                a[j] = __shfl(svB, k-16+j, 16);
                e[j] = __shfl(exB, k-16+j, 16);
            }
        }
        half4 q[8];
        #pragma unroll
        for (int j = 0; j < 8; j++) q[j] = z4[a[j]*16 + sl];
        #pragma unroll
        for (int j = 0; j < 8; j++) {
            float4 r = h4_to_f4(q[j]);
            acc.x += e[j]*r.x; acc.y += e[j]*r.y;
            acc.z += e[j]*r.z; acc.w += e[j]*r.w;
        }
    }
    for (; k + 4 <= lim; k += 4) {
        int a[4]; float e[4];
        if (k < 16) {
            #pragma unroll
            for (int j = 0; j < 4; j++) {
                a[j] = __shfl(svA, k+j, 16);
                e[j] = __shfl(exA, k+j, 16);
            }
        } else {
            #pragma unroll
            for (int j = 0; j < 4; j++) {
                a[j] = __shfl(svB, k-16+j, 16);
                e[j] = __shfl(exB, k-16+j, 16);
            }
        }
        half4 q[4];
        #pragma unroll
        for (int j = 0; j < 4; j++) q[j] = z4[a[j]*16 + sl];
        #pragma unroll
        for (int j = 0; j < 4; j++) {
            float4 r = h4_to_f4(q[j]);
            acc.x += e[j]*r.x; acc.y += e[j]*r.y;
            acc.z += e[j]*r.z; acc.w += e[j]*r.w;
        }
    }
    for (; k < lim; k++) {
        int a; float e2;
        if (k < 16) { a = __shfl(svA, k, 16);    e2 = __shfl(exA, k, 16); }
        else        { a = __shfl(svB, k-16, 16); e2 = __shfl(exB, k-16, 16); }
        float4 zr = h4_to_f4(z4[a*16 + sl]);
        acc.x += e2*zr.x; acc.y += e2*zr.y; acc.z += e2*zr.z; acc.w += e2*zr.w;
    }
    for (int kk = beg + 32; kk < end; kk++) {   // rare: deg > 32
        int sv = csr_src[kk];
        float v = es[sv] + edi;
        float e2 = exp2f(fmaxf(v, 0.2f * v));
        s += e2;
        float4 zr = h4_to_f4(z4[sv*16 + sl]);
        acc.x += e2*zr.x; acc.y += e2*zr.y; acc.z += e2*zr.z; acc.w += e2*zr.w;
    }
    float inv = 1.f / (s + 1e-16f);
    float4 bg4 = ((const float4*)bg)[sl];
    float4 o;
    o.x = fmaxf(acc.x*inv + bg4.x, 0.f);
    o.y = fmaxf(acc.y*inv + bg4.y, 0.f);
    o.z = fmaxf(acc.z*inv + bg4.z, 0.f);
    o.w = fmaxf(acc.w*inv + bg4.w, 0.f);
    if (apply_film) {
        int g = batch[i];
        const float4* gb4 = (const float4*)gb;
        float4 ga = gb4[g*32 + sl];
        float4 be = gb4[g*32 + 16 + sl];
        o.x = o.x*(1.f+ga.x) + be.x;
        o.y = o.y*(1.f+ga.y) + be.y;
        o.z = o.z*(1.f+ga.z) + be.z;
        o.w = o.w*(1.f+ga.w) + be.w;
    }
    half4 hv;
    hv.x = (half_t)o.x; hv.y = (half_t)o.y; hv.z = (half_t)o.z; hv.w = (half_t)o.w;
    ((half4*)hout)[i*16 + sl] = hv;
}

// ---------------- MFMA head: out = relu(h@Wc1+bc1)@Wc2+bc2 + 0.03*flags -----
__global__ __launch_bounds__(256) void k_head_mfma(
        const half_t* __restrict__ h, const float* __restrict__ x,
        const float* __restrict__ Wc1, const float* __restrict__ bc1,
        const float* __restrict__ Wc2, const float* __restrict__ bc2,
        const float* __restrict__ Wh1, const float* __restrict__ bh1,
        const float* __restrict__ Wh2, const float* __restrict__ bh2,
        float* __restrict__ out) {
    int wave = threadIdx.x >> 6;
    int l    = threadIdx.x & 63;
    int c    = l & 15;
    int g    = l >> 4;
    (void)wave;
    half8 Bf[2][4];
    #pragma unroll
    for (int ko = 0; ko < 2; ko++) {
        #pragma unroll
        for (int nt = 0; nt < 4; nt++) {
            half8 b;
            #pragma unroll
            for (int j = 0; j < 8; j++)
                b[j] = (half_t)Wc1[(ko*32 + g*8 + j)*64 + c + 16*nt];
            Bf[ko][nt] = b;
        }
    }
    float bc1v[4];
    float4 w2[4];
    #pragma unroll
    for (int nt = 0; nt < 4; nt++) {
        bc1v[nt] = bc1[c + 16*nt];
        w2[nt] = ((const float4*)Wc2)[c + 16*nt];   // Wc2 row (c+16nt), 4 outputs
    }
    int nWaves = gridDim.x * 4;
    int wid = blockIdx.x * 4 + (threadIdx.x >> 6);
    for (int t = wid; t < N_TILES; t += nWaves) {
        int m0 = t * 16;
        const half8* hrow = (const half8*)(h + (size_t)(m0 + c) * 64);
        half8 A0 = hrow[g];
        half8 A1 = hrow[g + 4];
        floatx4 D[4];
        #pragma unroll
        for (int nt = 0; nt < 4; nt++) {
            floatx4 acc = {0.f, 0.f, 0.f, 0.f};
            acc = __builtin_amdgcn_mfma_f32_16x16x32_f16(A0, Bf[0][nt], acc, 0, 0, 0);
            acc = __builtin_amdgcn_mfma_f32_16x16x32_f16(A1, Bf[1][nt], acc, 0, 0, 0);
            D[nt] = acc;
        }
        #pragma unroll
        for (int r = 0; r < 4; r++) {
            float4 p = {0.f, 0.f, 0.f, 0.f};
            #pragma unroll
            for (int nt = 0; nt < 4; nt++) {
                float tv = fmaxf(D[nt][r] + bc1v[nt], 0.f);
                p.x += tv * w2[nt].x;
                p.y += tv * w2[nt].y;
                p.z += tv * w2[nt].z;
                p.w += tv * w2[nt].w;
            }
            #pragma unroll
            for (int off = 1; off < 16; off <<= 1) {
                p.x += __shfl_xor(p.x, off, 16);
                p.y += __shfl_xor(p.y, off, 16);
                p.z += __shfl_xor(p.z, off, 16);
                p.w += __shfl_xor(p.w, off, 16);
            }
            if (c == 0) {
                int m = m0 + g*4 + r;
                float f0 = x[m*8+6], f1 = x[m*8+7];
                float t8[8];
                #pragma unroll
                for (int q = 0; q < 8; q++)
                    t8[q] = fmaxf(f0*Wh1[q] + f1*Wh1[8+q] + bh1[q], 0.f);
                float fl[4];
                #pragma unroll
                for (int q = 0; q < 4; q++) {
                    float a = bh2[q];
                    #pragma unroll
                    for (int rr = 0; rr < 8; rr++) a += t8[rr]*Wh2[rr*4+q];
                    fl[q] = a;
                }
                float4 ov;
                ov.x = p.x + bc2[0] + 0.03f*fl[0];
                ov.y = p.y + bc2[1] + 0.03f*fl[1];
                ov.z = p.z + bc2[2] + 0.03f*fl[2];
                ov.w = p.w + bc2[3] + 0.03f*fl[3];
                ((float4*)out)[m] = ov;
            }
        }
    }
}

extern "C" void kernel_launch(void* const* d_in, const int* in_sizes, int n_in,
                              void* d_out, int out_size, void* d_ws, size_t ws_size,
                              hipStream_t stream) {
    const float* x       = (const float*)d_in[0];
    const int*   ei      = (const int*)  d_in[1];
    const int*   batch   = (const int*)  d_in[2];
    const float* climber = (const float*)d_in[3];
    const float* W_in    = (const float*)d_in[4];
    const float* b_in    = (const float*)d_in[5];
    const float* ln_g    = (const float*)d_in[6];
    const float* ln_b    = (const float*)d_in[7];
    const float* W_c     = (const float*)d_in[8];
    const float* b_c     = (const float*)d_in[9];
    const float* Wf1     = (const float*)d_in[10];
    const float* bf1     = (const float*)d_in[11];
    const float* Wf2     = (const float*)d_in[12];
    const float* bf2     = (const float*)d_in[13];
    const float* Wg1     = (const float*)d_in[14];
    const float* as1     = (const float*)d_in[15];
    const float* ad1     = (const float*)d_in[16];
    const float* bg1     = (const float*)d_in[17];
    const float* Wg2     = (const float*)d_in[18];
    const float* as2     = (const float*)d_in[19];
    const float* ad2     = (const float*)d_in[20];
    const float* bg2     = (const float*)d_in[21];
    const float* Wc1     = (const float*)d_in[22];
    const float* bc1     = (const float*)d_in[23];
    const float* Wc2     = (const float*)d_in[24];
    const float* bc2     = (const float*)d_in[25];
    const float* Wh1     = (const float*)d_in[26];
    const float* bh1     = (const float*)d_in[27];
    const float* Wh2     = (const float*)d_in[28];
    const float* bh2     = (const float*)d_in[29];
    float* out = (float*)d_out;
    float* ws  = (float*)d_ws;

    // workspace carve (floats); h and z ping-pong through the whole net
    float*  gb1         = ws;                       // 128,000
    float*  gb2         = gb1 + 128000;             // 128,000
    half_t* hbuf        = (half_t*)(gb2 + 128000);  // 6.4M halfs
    half_t* zbuf        = hbuf + 6400000;           // 6.4M halfs
    float*  es          = (float*)(zbuf + 6400000); // 100,000
    float*  ed          = es + N_NODES;             // 100,000
    int*    rowptr      = (int*)(ed + N_NODES);     // 100,001
    int*    csr_src     = rowptr + N_NODES + 1;     // 1,200,000
    int*    bucket_cnt  = csr_src + N_EDGES;        // 256 (memset start)
    int*    bucket_fill = bucket_cnt + NBUCK;       // 256 (memset end)
    int*    bucket_base = bucket_fill + NBUCK;      // 257
    int*    staged      = bucket_base + NBUCK + 1;  // 1,200,000

    // CSR build via bucket sort (topology is layer-invariant)
    hipMemsetAsync(bucket_cnt, 0, 2*NBUCK*sizeof(int), stream);
    k_bhist<<<S3_BLOCKS, 1024, 0, stream>>>(ei, bucket_cnt);
    k_bscan<<<1, NBUCK, 0, stream>>>(bucket_cnt, bucket_base);
    k_bin  <<<S3_BLOCKS, 1024, 0, stream>>>(ei, bucket_base, bucket_fill, staged);
    k_bcsr <<<NBUCK, 1024, 0, stream>>>(staged, bucket_base, rowptr, csr_src);

    // prologue (fused LN + FiLM coefficients)
    k_climber_film<<<N_GRAPHS, 128, 0, stream>>>(climber, ln_g, ln_b, W_c, b_c,
                                                 Wf1, bf1, Wf2, bf2, gb1, gb2);

    int nodeBlocks = (N_NODES*16 + 255)/256;   // 6250
    k_node0<<<nodeBlocks, 256, 0, stream>>>(x, batch, W_in, b_in, gb1, hbuf);
    k_mfma_z<<<MFMA_BLOCKS, 256, 0, stream>>>(hbuf, Wg1, as1, ad1, zbuf, es, ed);
    k_agg<<<nodeBlocks, 256, 0, stream>>>(rowptr, csr_src, es, ed, zbuf, bg1,
                                          batch, gb2, 1, hbuf);
    k_mfma_z<<<MFMA_BLOCKS, 256, 0, stream>>>(hbuf, Wg2, as2, ad2, zbuf, es, ed);
    k_agg<<<nodeBlocks, 256, 0, stream>>>(rowptr, csr_src, es, ed, zbuf, bg2,
                                          batch, gb2, 0, hbuf);
    k_head_mfma<<<MFMA_BLOCKS, 256, 0, stream>>>(hbuf, x, Wc1, bc1, Wc2, bc2,
                                                 Wh1, bh1, Wh2, bh2, out);
}